// Round 1
// 160.800 us; speedup vs baseline: 1.0408x; 1.0408x over previous
//
#include <hip/hip_runtime.h>
#include <hip/hip_fp16.h>
#include <cmath>

typedef _Float16 half8 __attribute__((ext_vector_type(8)));
typedef _Float16 half4_t __attribute__((ext_vector_type(4)));
typedef float f32x4 __attribute__((ext_vector_type(4)));

#define LDIM 4096
#define DDIM 1024
#define NSTATE 16
#define NCHUNK 128
#define CLEN 32

#define GLD16(g, l) __builtin_amdgcn_global_load_lds( \
    (const __attribute__((address_space(1))) void*)(g), \
    (__attribute__((address_space(3))) void*)(l), 16, 0, 0)

// ---------------- K1: prep (W transpose + BC pack) + RMSNorm ----------------
__global__ __launch_bounds__(256) void k_prep_norm(const float* __restrict__ x,
                                                   const float* __restrict__ nw,
                                                   const float* __restrict__ W,
                                                   const float* __restrict__ WB,
                                                   const float* __restrict__ WC,
                                                   _Float16* __restrict__ xnh,
                                                   _Float16* __restrict__ Wt,
                                                   _Float16* __restrict__ BCe) {
  const int b = blockIdx.x, t = threadIdx.x;
  if (b < 4096) {
    const int l = b;
    float4 v = ((const float4*)(x + (size_t)l * DDIM))[t];
    float ss = v.x * v.x + v.y * v.y + v.z * v.z + v.w * v.w;
#pragma unroll
    for (int off = 32; off; off >>= 1) ss += __shfl_xor(ss, off, 64);
    __shared__ float sred[4];
    if ((t & 63) == 0) sred[t >> 6] = ss;
    __syncthreads();
    float tot = sred[0] + sred[1] + sred[2] + sred[3];
    float r = rsqrtf(tot * (1.0f / (float)DDIM) + 1e-6f);
    float4 wv = ((const float4*)nw)[t];
    half4_t h;
    h[0] = (_Float16)(v.x * wv.x * r); h[1] = (_Float16)(v.y * wv.y * r);
    h[2] = (_Float16)(v.z * wv.z * r); h[3] = (_Float16)(v.w * wv.w * r);
    ((half4_t*)(xnh + (size_t)l * DDIM))[t] = h;
  } else if (b < 4352) {
    __shared__ float tile[64][65];
    const int bb = b - 4096;
    const int n0 = (bb & 15) * 64, k0 = (bb >> 4) * 64;
#pragma unroll
    for (int i = 0; i < 16; ++i) {
      int idx = t + i * 256;
      int kk = idx >> 6, nn = idx & 63;
      tile[kk][nn] = W[(size_t)(k0 + kk) * DDIM + n0 + nn];
    }
    __syncthreads();
#pragma unroll
    for (int i = 0; i < 16; ++i) {
      int idx = t + i * 256;
      int nn = idx >> 6, kk = idx & 63;
      Wt[(size_t)(n0 + nn) * DDIM + k0 + kk] = (_Float16)tile[kk][nn];
    }
  } else {
    const int by2 = b - 4352;
#pragma unroll
    for (int rr = 0; rr < 2; ++rr) {
      int r = 2 * by2 + rr;
      const float* src = (r & 1) ? WC : WB;
      int n = r >> 1;
#pragma unroll
      for (int j = 0; j < 4; ++j) {
        int k = t * 4 + j;
        BCe[(size_t)r * DDIM + k] = (_Float16)src[(size_t)k * NSTATE + n];
      }
    }
  }
}

// ---------------- K2: GEMM, BK=64, XOR-swizzled LDS, atomic-free BC ----------------
// Tile M=128, N=64. grid 512: bx = bid&15 (N), by = bid>>4 (M). 4 waves 2x2,
// wave tile 64x32. GLD16 double-buffered staging, 16 K-steps of BK=64.
// LDS 16B-slot swizzle: slot ^= (row&7), applied via pre-swizzled GLOBAL source
// (GLD16 dest must stay linear) + swizzled ds_read. Even bank spread preserved.
// BC GEMM: bx==0 blocks compute the FULL K sum and store bpc directly (no atomics).
__global__ __launch_bounds__(256, 2) void k_gemm64(const _Float16* __restrict__ Ah,
                                                   const _Float16* __restrict__ Bh,
                                                   const _Float16* __restrict__ B2h,
                                                   const float* __restrict__ b_delta,
                                                   _Float16* __restrict__ sdh,
                                                   float* __restrict__ bpc) {
  __shared__ __align__(16) _Float16 As[2][128 * 64];   // 32 KB
  __shared__ __align__(16) _Float16 Bs[2][64 * 64];    // 16 KB
  __shared__ __align__(16) _Float16 B2s[2][32 * 64];   //  8 KB
  const int t = threadIdx.x;
  const int w = t >> 6, lane = t & 63;
  const int quad = lane >> 4, l16 = lane & 15;
  const int wr = w >> 1, wc = w & 1;
  const int bid = blockIdx.x;
  const int bx = bid & 15, by = bid >> 4;
  const int tileM = by * 128, tileN = bx * 64;
  // staging geometry: one GLD16 covers 8 rows x 128B; lane -> (row=l>>3, slot=l&7)
  const int srow = lane >> 3;
  const int sslot = (lane & 7) ^ srow;   // pre-swizzled 16B slot in global source
  const _Float16* gA0 = Ah + (size_t)(tileM + w * 32 + srow) * DDIM + sslot * 8;
  const _Float16* gB0 = Bh + (size_t)(tileN + w * 16 + srow) * DDIM + sslot * 8;
  const _Float16* gC0 = B2h + (size_t)(w * 8 + srow) * DDIM + sslot * 8;

  f32x4 acc[4][2], acc2[4];
#pragma unroll
  for (int i = 0; i < 4; ++i) {
    acc2[i] = (f32x4){0.f, 0.f, 0.f, 0.f};
#pragma unroll
    for (int j = 0; j < 2; ++j) acc[i][j] = (f32x4){0.f, 0.f, 0.f, 0.f};
  }

  auto stage = [&](int kt, int p) {
    const int ko = kt * 64;
#pragma unroll
    for (int g = 0; g < 4; ++g)
      GLD16(gA0 + (size_t)g * 8 * DDIM + ko, &As[p][(w * 32 + g * 8) * 64]);
#pragma unroll
    for (int g = 0; g < 2; ++g)
      GLD16(gB0 + (size_t)g * 8 * DDIM + ko, &Bs[p][(w * 16 + g * 8) * 64]);
    if (bx == 0)
      GLD16(gC0 + ko, &B2s[p][(w * 8) * 64]);
  };

  stage(0, 0);
  for (int kt = 0; kt < 16; ++kt) {
    const int p = kt & 1;
    __syncthreads();               // drains vmcnt: buf p staged; guards p^1 overwrite
    if (kt < 15) stage(kt + 1, p ^ 1);
#pragma unroll
    for (int ks = 0; ks < 2; ++ks) {
      const int sw = ((ks * 4 + quad) ^ (l16 & 7)) * 8;  // swizzled 16B slot (halfs)
      half8 af[4], bf[2];
#pragma unroll
      for (int i = 0; i < 4; ++i)
        af[i] = *(const half8*)&As[p][(wr * 64 + i * 16 + l16) * 64 + sw];
#pragma unroll
      for (int j = 0; j < 2; ++j)
        bf[j] = *(const half8*)&Bs[p][(wc * 32 + j * 16 + l16) * 64 + sw];
#pragma unroll
      for (int i = 0; i < 4; ++i)
#pragma unroll
        for (int j = 0; j < 2; ++j)
          acc[i][j] = __builtin_amdgcn_mfma_f32_16x16x32_f16(af[i], bf[j], acc[i][j], 0, 0, 0);
      if (bx == 0) {
        half8 cf = *(const half8*)&B2s[p][(wc * 16 + l16) * 64 + sw];
#pragma unroll
        for (int i = 0; i < 4; ++i)
          acc2[i] = __builtin_amdgcn_mfma_f32_16x16x32_f16(af[i], cf, acc2[i], 0, 0, 0);
      }
    }
  }

  // epilogue: delta = soft_clamp(softplus(z+b)) -> sdh = sqrt(delta) f16
  const float cC = 5.00005f, cH = 4.99995f, invH = 1.0f / 4.99995f;
  float bdl[2];
#pragma unroll
  for (int j = 0; j < 2; ++j) bdl[j] = b_delta[tileN + wc * 32 + j * 16 + l16];
#pragma unroll
  for (int i = 0; i < 4; ++i) {
#pragma unroll
    for (int r = 0; r < 4; ++r) {
      int row = tileM + wr * 64 + i * 16 + quad * 4 + r;
#pragma unroll
      for (int j = 0; j < 2; ++j) {
        int col = tileN + wc * 32 + j * 16 + l16;
        float z = acc[i][j][r] + bdl[j];
        float e = __expf(-fabsf(z));
        float sp = fmaxf(z, 0.f) + __logf(1.0f + e);
        float tt = (sp - cC) * invH;
        float e2 = __expf(-2.0f * fabsf(tt));
        float th = copysignf((1.0f - e2) / (1.0f + e2), tt);
        float dt = fmaf(cH, th, cC);
        sdh[(size_t)row * DDIM + col] = (_Float16)sqrtf(dt);
      }
      if (bx == 0)
        bpc[(size_t)row * 32 + wc * 16 + l16] = acc2[i][r];
    }
  }
}

// ---------------- K3: per-chunk local scan -> {prodA, h_end} ----------------
__global__ __launch_bounds__(256) void k_scan1(const _Float16* __restrict__ sdh,
                                               const _Float16* __restrict__ xnh,
                                               const float* __restrict__ bpc,
                                               const float* __restrict__ A_log,
                                               float2* __restrict__ Ph) {
  __shared__ float2 bcs[CLEN * NSTATE];
  const int t = threadIdx.x;
  const int d = blockIdx.x * 256 + t;
  const int c = blockIdx.y;
#pragma unroll
  for (int u = t; u < CLEN * NSTATE; u += 256) {
    int l = u >> 4, n2 = (u & 15) * 2;
    bcs[u] = *(const float2*)&bpc[(size_t)(c * CLEN + l) * 32 + n2];
  }
  float halfA[NSTATE], h[NSTATE], P[NSTATE];
#pragma unroll
  for (int n = 0; n < NSTATE; ++n) {
    halfA[n] = -0.5f * __expf(A_log[d * NSTATE + n]);
    h[n] = 0.f; P[n] = 1.f;
  }
  __syncthreads();
  const _Float16* sdr = sdh + (size_t)c * CLEN * DDIM + d;
  const _Float16* xr = xnh + (size_t)c * CLEN * DDIM + d;
#pragma unroll 2
  for (int i = 0; i < CLEN; ++i) {
    float sdv = (float)sdr[(size_t)i * DDIM];
    float xv = (float)xr[(size_t)i * DDIM];
    float dsq = sdv * sdv;
    float sdx = sdv * xv;
#pragma unroll
    for (int n = 0; n < NSTATE; ++n) {
      float2 bc = bcs[i * NSTATE + n];
      float hd = dsq * halfA[n];
      float di = __builtin_amdgcn_rcpf(1.0f - hd);
      float ab = fmaf(hd, di, di);
      h[n] = fmaf(ab, h[n], sdx * bc.x * di);
      P[n] *= ab;
    }
  }
#pragma unroll
  for (int n = 0; n < NSTATE; ++n)
    Ph[((size_t)c * NSTATE + n) * DDIM + d] = make_float2(P[n], h[n]);
}

// ---------------- K4: sequential combine across chunks ----------------
__global__ __launch_bounds__(64) void k_comb(const float2* __restrict__ Ph,
                                             float* __restrict__ Hinit) {
  const int g = blockIdx.x * 64 + threadIdx.x;
  float H = 0.f;
  for (int cb = 0; cb < NCHUNK; cb += 8) {
    float2 ph[8];
#pragma unroll
    for (int u = 0; u < 8; ++u)
      ph[u] = Ph[(size_t)(cb + u) * (DDIM * NSTATE) + g];
#pragma unroll
    for (int u = 0; u < 8; ++u) {
      Hinit[(size_t)(cb + u) * (DDIM * NSTATE) + g] = H;
      H = fmaf(ph[u].x, H, ph[u].y);
    }
  }
}

// ---------------- K5: re-run chunk scans with true h0, emit y ----------------
__global__ __launch_bounds__(256) void k_scan2(const _Float16* __restrict__ sdh,
                                               const _Float16* __restrict__ xnh,
                                               const float* __restrict__ bpc,
                                               const float* __restrict__ A_log,
                                               const float* __restrict__ Hinit,
                                               const float* __restrict__ Dskip,
                                               float* __restrict__ y) {
  __shared__ float2 bcs[CLEN * NSTATE];
  const int t = threadIdx.x;
  const int d = blockIdx.x * 256 + t;
  const int c = blockIdx.y;
#pragma unroll
  for (int u = t; u < CLEN * NSTATE; u += 256) {
    int l = u >> 4, n2 = (u & 15) * 2;
    bcs[u] = *(const float2*)&bpc[(size_t)(c * CLEN + l) * 32 + n2];
  }
  float halfA[NSTATE], h[NSTATE];
#pragma unroll
  for (int n = 0; n < NSTATE; ++n) {
    halfA[n] = -0.5f * __expf(A_log[d * NSTATE + n]);
    h[n] = Hinit[(size_t)c * (DDIM * NSTATE) + n * DDIM + d];
  }
  const float dsk = Dskip[d];
  __syncthreads();
  const _Float16* sdr = sdh + (size_t)c * CLEN * DDIM + d;
  const _Float16* xr = xnh + (size_t)c * CLEN * DDIM + d;
  float* yr = y + (size_t)c * CLEN * DDIM + d;
#pragma unroll 2
  for (int i = 0; i < CLEN; ++i) {
    float sdv = (float)sdr[(size_t)i * DDIM];
    float xv = (float)xr[(size_t)i * DDIM];
    float dsq = sdv * sdv;
    float sdx = sdv * xv;
    float acc = dsk * xv;
#pragma unroll
    for (int n = 0; n < NSTATE; ++n) {
      float2 bc = bcs[i * NSTATE + n];
      float hd = dsq * halfA[n];
      float di = __builtin_amdgcn_rcpf(1.0f - hd);
      float ab = fmaf(hd, di, di);
      h[n] = fmaf(ab, h[n], sdx * bc.x * di);
      acc = fmaf(bc.y, h[n], acc);
    }
    yr[(size_t)i * DDIM] = acc;
  }
}

// ---------------- launch ----------------
extern "C" void kernel_launch(void* const* d_in, const int* in_sizes, int n_in,
                              void* d_out, int out_size, void* d_ws, size_t ws_size,
                              hipStream_t stream) {
  const float* x       = (const float*)d_in[0];
  const float* A_log   = (const float*)d_in[1];
  const float* W_delta = (const float*)d_in[2];
  const float* b_delta = (const float*)d_in[3];
  const float* W_B     = (const float*)d_in[4];
  const float* W_C     = (const float*)d_in[5];
  const float* D_skip  = (const float*)d_in[6];
  const float* norm_w  = (const float*)d_in[7];
  float* y = (float*)d_out;

  char* ws = (char*)d_ws;
  const size_t MB = 1024 * 1024;
  _Float16* xnh = (_Float16*)(ws);              //  8 MB xn f16
  _Float16* Wt  = (_Float16*)(ws + 8 * MB);     //  2 MB W_delta^T f16
  _Float16* BCe = (_Float16*)(ws + 10 * MB);    // 64 KB packed W_B/W_C f16 (32 x 1024)
  _Float16* sdh = (_Float16*)(ws + 11 * MB);    //  8 MB sqrt(delta) f16
  float*    bpc = (float*)(ws + 19 * MB);       // 512 KB BC result [4096][32]
  float2*   Ph  = (float2*)(ws + 20 * MB);      // 16 MB {prodA, h_end}
  float*    Hin = (float*)(ws + 36 * MB);       //  8 MB chunk-entry states
  (void)ws_size; (void)in_sizes; (void)n_in; (void)out_size;

  hipLaunchKernelGGL(k_prep_norm, dim3(4368), dim3(256), 0, stream,
                     x, norm_w, W_delta, W_B, W_C, xnh, Wt, BCe);
  hipLaunchKernelGGL(k_gemm64, dim3(512), dim3(256), 0, stream,
                     xnh, Wt, BCe, b_delta, sdh, bpc);
  hipLaunchKernelGGL(k_scan1, dim3(4, NCHUNK), dim3(256), 0, stream,
                     sdh, xnh, bpc, A_log, Ph);
  hipLaunchKernelGGL(k_comb, dim3(256), dim3(64), 0, stream, Ph, Hin);
  hipLaunchKernelGGL(k_scan2, dim3(4, NCHUNK), dim3(256), 0, stream,
                     sdh, xnh, bpc, A_log, Hin, D_skip, y);
}

// Round 2
// 158.903 us; speedup vs baseline: 1.0532x; 1.0119x over previous
//
#include <hip/hip_runtime.h>
#include <hip/hip_fp16.h>
#include <cmath>

typedef _Float16 half8 __attribute__((ext_vector_type(8)));
typedef _Float16 half4_t __attribute__((ext_vector_type(4)));
typedef _Float16 half2_t __attribute__((ext_vector_type(2)));
typedef float f32x4 __attribute__((ext_vector_type(4)));
typedef float f32x2 __attribute__((ext_vector_type(2)));

#define LDIM 4096
#define DDIM 1024
#define NSTATE 16
#define NCHUNK 128
#define CLEN 32

#define GLD16(g, l) __builtin_amdgcn_global_load_lds( \
    (const __attribute__((address_space(1))) void*)(g), \
    (__attribute__((address_space(3))) void*)(l), 16, 0, 0)

// ---------------- K1: prep (W transpose + BC pack planar) + RMSNorm ----------------
__global__ __launch_bounds__(256) void k_prep_norm(const float* __restrict__ x,
                                                   const float* __restrict__ nw,
                                                   const float* __restrict__ W,
                                                   const float* __restrict__ WB,
                                                   const float* __restrict__ WC,
                                                   _Float16* __restrict__ xnh,
                                                   _Float16* __restrict__ Wt,
                                                   _Float16* __restrict__ BCe) {
  const int b = blockIdx.x, t = threadIdx.x;
  if (b < 4096) {
    const int l = b;
    float4 v = ((const float4*)(x + (size_t)l * DDIM))[t];
    float ss = v.x * v.x + v.y * v.y + v.z * v.z + v.w * v.w;
#pragma unroll
    for (int off = 32; off; off >>= 1) ss += __shfl_xor(ss, off, 64);
    __shared__ float sred[4];
    if ((t & 63) == 0) sred[t >> 6] = ss;
    __syncthreads();
    float tot = sred[0] + sred[1] + sred[2] + sred[3];
    float r = rsqrtf(tot * (1.0f / (float)DDIM) + 1e-6f);
    float4 wv = ((const float4*)nw)[t];
    half4_t h;
    h[0] = (_Float16)(v.x * wv.x * r); h[1] = (_Float16)(v.y * wv.y * r);
    h[2] = (_Float16)(v.z * wv.z * r); h[3] = (_Float16)(v.w * wv.w * r);
    ((half4_t*)(xnh + (size_t)l * DDIM))[t] = h;
  } else if (b < 4352) {
    __shared__ float tile[64][65];
    const int bb = b - 4096;
    const int n0 = (bb & 15) * 64, k0 = (bb >> 4) * 64;
#pragma unroll
    for (int i = 0; i < 16; ++i) {
      int idx = t + i * 256;
      int kk = idx >> 6, nn = idx & 63;
      tile[kk][nn] = W[(size_t)(k0 + kk) * DDIM + n0 + nn];
    }
    __syncthreads();
#pragma unroll
    for (int i = 0; i < 16; ++i) {
      int idx = t + i * 256;
      int nn = idx >> 6, kk = idx & 63;
      Wt[(size_t)(n0 + nn) * DDIM + k0 + kk] = (_Float16)tile[kk][nn];
    }
  } else {
    // planar pack: rows 0..15 = W_B cols, rows 16..31 = W_C cols
    const int by2 = b - 4352;
#pragma unroll
    for (int rr = 0; rr < 2; ++rr) {
      int r = 2 * by2 + rr;
      const float* src = (r < 16) ? WB : WC;
      int n = r & 15;
#pragma unroll
      for (int j = 0; j < 4; ++j) {
        int k = t * 4 + j;
        BCe[(size_t)r * DDIM + k] = (_Float16)src[(size_t)k * NSTATE + n];
      }
    }
  }
}

// ---------------- K2: GEMM, BK=64, XOR-swizzled LDS, atomic-free BC ----------------
// Epilogue now writes packed half2{sqrt(delta), xn} so scan kernels do 1x4B load.
__global__ __launch_bounds__(256, 2) void k_gemm64(const _Float16* __restrict__ Ah,
                                                   const _Float16* __restrict__ Bh,
                                                   const _Float16* __restrict__ B2h,
                                                   const float* __restrict__ b_delta,
                                                   half2_t* __restrict__ sxh,
                                                   float* __restrict__ bpc) {
  __shared__ __align__(16) _Float16 As[2][128 * 64];   // 32 KB
  __shared__ __align__(16) _Float16 Bs[2][64 * 64];    // 16 KB
  __shared__ __align__(16) _Float16 B2s[2][32 * 64];   //  8 KB
  const int t = threadIdx.x;
  const int w = t >> 6, lane = t & 63;
  const int quad = lane >> 4, l16 = lane & 15;
  const int wr = w >> 1, wc = w & 1;
  const int bid = blockIdx.x;
  const int bx = bid & 15, by = bid >> 4;
  const int tileM = by * 128, tileN = bx * 64;
  const int srow = lane >> 3;
  const int sslot = (lane & 7) ^ srow;   // pre-swizzled 16B slot in global source
  const _Float16* gA0 = Ah + (size_t)(tileM + w * 32 + srow) * DDIM + sslot * 8;
  const _Float16* gB0 = Bh + (size_t)(tileN + w * 16 + srow) * DDIM + sslot * 8;
  const _Float16* gC0 = B2h + (size_t)(w * 8 + srow) * DDIM + sslot * 8;

  f32x4 acc[4][2], acc2[4];
#pragma unroll
  for (int i = 0; i < 4; ++i) {
    acc2[i] = (f32x4){0.f, 0.f, 0.f, 0.f};
#pragma unroll
    for (int j = 0; j < 2; ++j) acc[i][j] = (f32x4){0.f, 0.f, 0.f, 0.f};
  }

  auto stage = [&](int kt, int p) {
    const int ko = kt * 64;
#pragma unroll
    for (int g = 0; g < 4; ++g)
      GLD16(gA0 + (size_t)g * 8 * DDIM + ko, &As[p][(w * 32 + g * 8) * 64]);
#pragma unroll
    for (int g = 0; g < 2; ++g)
      GLD16(gB0 + (size_t)g * 8 * DDIM + ko, &Bs[p][(w * 16 + g * 8) * 64]);
    if (bx == 0)
      GLD16(gC0 + ko, &B2s[p][(w * 8) * 64]);
  };

  stage(0, 0);
  for (int kt = 0; kt < 16; ++kt) {
    const int p = kt & 1;
    __syncthreads();               // drains vmcnt: buf p staged; guards p^1 overwrite
    if (kt < 15) stage(kt + 1, p ^ 1);
#pragma unroll
    for (int ks = 0; ks < 2; ++ks) {
      const int sw = ((ks * 4 + quad) ^ (l16 & 7)) * 8;  // swizzled 16B slot (halfs)
      half8 af[4], bf[2];
#pragma unroll
      for (int i = 0; i < 4; ++i)
        af[i] = *(const half8*)&As[p][(wr * 64 + i * 16 + l16) * 64 + sw];
#pragma unroll
      for (int j = 0; j < 2; ++j)
        bf[j] = *(const half8*)&Bs[p][(wc * 32 + j * 16 + l16) * 64 + sw];
#pragma unroll
      for (int i = 0; i < 4; ++i)
#pragma unroll
        for (int j = 0; j < 2; ++j)
          acc[i][j] = __builtin_amdgcn_mfma_f32_16x16x32_f16(af[i], bf[j], acc[i][j], 0, 0, 0);
      if (bx == 0) {
        half8 cf = *(const half8*)&B2s[p][(wc * 16 + l16) * 64 + sw];
#pragma unroll
        for (int i = 0; i < 4; ++i)
          acc2[i] = __builtin_amdgcn_mfma_f32_16x16x32_f16(af[i], cf, acc2[i], 0, 0, 0);
      }
    }
  }

  // epilogue: delta = soft_clamp(softplus(z+b)); write {sqrt(delta), xn} packed
  const float cC = 5.00005f, cH = 4.99995f, invH = 1.0f / 4.99995f;
  float bdl[2];
#pragma unroll
  for (int j = 0; j < 2; ++j) bdl[j] = b_delta[tileN + wc * 32 + j * 16 + l16];
#pragma unroll
  for (int i = 0; i < 4; ++i) {
#pragma unroll
    for (int r = 0; r < 4; ++r) {
      int row = tileM + wr * 64 + i * 16 + quad * 4 + r;
#pragma unroll
      for (int j = 0; j < 2; ++j) {
        int col = tileN + wc * 32 + j * 16 + l16;
        float z = acc[i][j][r] + bdl[j];
        float e = __expf(-fabsf(z));
        float sp = fmaxf(z, 0.f) + __logf(1.0f + e);
        float tt = (sp - cC) * invH;           // tt in [-1, ~1]: exp(2tt) safe
        float e2 = __expf(2.0f * tt);
        float th = 1.0f - 2.0f * __builtin_amdgcn_rcpf(e2 + 1.0f);
        float dt = fmaf(cH, th, cC);
        half2_t pk;
        pk[0] = (_Float16)sqrtf(dt);
        pk[1] = Ah[(size_t)row * DDIM + col];
        sxh[(size_t)row * DDIM + col] = pk;
      }
      if (bx == 0)
        bpc[(size_t)row * 32 + wc * 16 + l16] = acc2[i][r];
    }
  }
}

// ---------------- K3: per-chunk local scan -> {prodA, h_end} ----------------
// bc coefs read uniformly from global (scalar s_load path); packed f32x2 math.
__global__ __launch_bounds__(256) void k_scan1(const half2_t* __restrict__ sxh,
                                               const float* __restrict__ bpc,
                                               const float* __restrict__ A_log,
                                               float2* __restrict__ Ph) {
  const int t = threadIdx.x;
  const int d = blockIdx.x * 256 + t;
  const int c = blockIdx.y;
  const float4* alp = (const float4*)(A_log + (size_t)d * NSTATE);
  f32x2 halfA[8], h[8], P[8];
#pragma unroll
  for (int q = 0; q < 4; ++q) {
    float4 al = alp[q];
    halfA[2 * q + 0] = (f32x2){-0.5f * __expf(al.x), -0.5f * __expf(al.y)};
    halfA[2 * q + 1] = (f32x2){-0.5f * __expf(al.z), -0.5f * __expf(al.w)};
  }
#pragma unroll
  for (int j = 0; j < 8; ++j) { h[j] = (f32x2){0.f, 0.f}; P[j] = (f32x2){1.f, 1.f}; }
  const half2_t* sxr = sxh + (size_t)c * CLEN * DDIM + d;
  const float* bp0 = bpc + (size_t)c * CLEN * 32;
  const f32x2 one2 = {1.f, 1.f}, two2 = {2.f, 2.f}, mone2 = {-1.f, -1.f};
#pragma unroll 4
  for (int i = 0; i < CLEN; ++i) {
    half2_t sx = sxr[(size_t)i * DDIM];
    float sdv = (float)sx[0], xv = (float)sx[1];
    float dsq = sdv * sdv, sdx = sdv * xv;
    f32x2 dsq2 = {dsq, dsq}, sdx2 = {sdx, sdx};
    const float* bp = bp0 + i * 32;
#pragma unroll
    for (int j = 0; j < 8; ++j) {
      f32x2 bB = *(const f32x2*)(bp + 2 * j);              // uniform -> SGPR
      f32x2 hd = dsq2 * halfA[j];
      f32x2 om = one2 - hd;
      f32x2 di = {__builtin_amdgcn_rcpf(om[0]), __builtin_amdgcn_rcpf(om[1])};
      f32x2 ab = __builtin_elementwise_fma(di, two2, mone2);  // (1+hd)/(1-hd) = 2di-1
      h[j] = __builtin_elementwise_fma(ab, h[j], sdx2 * bB * di);
      P[j] = P[j] * ab;
    }
  }
#pragma unroll
  for (int j = 0; j < 8; ++j) {
    Ph[((size_t)c * NSTATE + 2 * j + 0) * DDIM + d] = make_float2(P[j][0], h[j][0]);
    Ph[((size_t)c * NSTATE + 2 * j + 1) * DDIM + d] = make_float2(P[j][1], h[j][1]);
  }
}

// ---------------- K4: sequential combine across chunks ----------------
__global__ __launch_bounds__(64) void k_comb(const float2* __restrict__ Ph,
                                             float* __restrict__ Hinit) {
  const int g = blockIdx.x * 64 + threadIdx.x;
  float H = 0.f;
  for (int cb = 0; cb < NCHUNK; cb += 16) {
    float2 ph[16];
#pragma unroll
    for (int u = 0; u < 16; ++u)
      ph[u] = Ph[(size_t)(cb + u) * (DDIM * NSTATE) + g];
#pragma unroll
    for (int u = 0; u < 16; ++u) {
      Hinit[(size_t)(cb + u) * (DDIM * NSTATE) + g] = H;
      H = fmaf(ph[u].x, H, ph[u].y);
    }
  }
}

// ---------------- K5: re-run chunk scans with true h0, emit y ----------------
__global__ __launch_bounds__(256) void k_scan2(const half2_t* __restrict__ sxh,
                                               const float* __restrict__ bpc,
                                               const float* __restrict__ A_log,
                                               const float* __restrict__ Hinit,
                                               const float* __restrict__ Dskip,
                                               float* __restrict__ y) {
  const int t = threadIdx.x;
  const int d = blockIdx.x * 256 + t;
  const int c = blockIdx.y;
  const float4* alp = (const float4*)(A_log + (size_t)d * NSTATE);
  f32x2 halfA[8], h[8];
#pragma unroll
  for (int q = 0; q < 4; ++q) {
    float4 al = alp[q];
    halfA[2 * q + 0] = (f32x2){-0.5f * __expf(al.x), -0.5f * __expf(al.y)};
    halfA[2 * q + 1] = (f32x2){-0.5f * __expf(al.z), -0.5f * __expf(al.w)};
  }
#pragma unroll
  for (int j = 0; j < 8; ++j)
    h[j] = (f32x2){Hinit[(size_t)c * (DDIM * NSTATE) + (size_t)(2 * j) * DDIM + d],
                   Hinit[(size_t)c * (DDIM * NSTATE) + (size_t)(2 * j + 1) * DDIM + d]};
  const float dsk = Dskip[d];
  const half2_t* sxr = sxh + (size_t)c * CLEN * DDIM + d;
  const float* bp0 = bpc + (size_t)c * CLEN * 32;
  float* yr = y + (size_t)c * CLEN * DDIM + d;
  const f32x2 one2 = {1.f, 1.f}, two2 = {2.f, 2.f}, mone2 = {-1.f, -1.f};
#pragma unroll 4
  for (int i = 0; i < CLEN; ++i) {
    half2_t sx = sxr[(size_t)i * DDIM];
    float sdv = (float)sx[0], xv = (float)sx[1];
    float dsq = sdv * sdv, sdx = sdv * xv;
    f32x2 dsq2 = {dsq, dsq}, sdx2 = {sdx, sdx};
    const float* bp = bp0 + i * 32;
    f32x2 acc = {0.f, 0.f};
#pragma unroll
    for (int j = 0; j < 8; ++j) {
      f32x2 bB = *(const f32x2*)(bp + 2 * j);              // uniform -> SGPR
      f32x2 bC = *(const f32x2*)(bp + 16 + 2 * j);         // uniform -> SGPR
      f32x2 hd = dsq2 * halfA[j];
      f32x2 om = one2 - hd;
      f32x2 di = {__builtin_amdgcn_rcpf(om[0]), __builtin_amdgcn_rcpf(om[1])};
      f32x2 ab = __builtin_elementwise_fma(di, two2, mone2);
      h[j] = __builtin_elementwise_fma(ab, h[j], sdx2 * bB * di);
      acc = __builtin_elementwise_fma(bC, h[j], acc);
    }
    yr[(size_t)i * DDIM] = fmaf(dsk, xv, acc[0] + acc[1]);
  }
}

// ---------------- launch ----------------
extern "C" void kernel_launch(void* const* d_in, const int* in_sizes, int n_in,
                              void* d_out, int out_size, void* d_ws, size_t ws_size,
                              hipStream_t stream) {
  const float* x       = (const float*)d_in[0];
  const float* A_log   = (const float*)d_in[1];
  const float* W_delta = (const float*)d_in[2];
  const float* b_delta = (const float*)d_in[3];
  const float* W_B     = (const float*)d_in[4];
  const float* W_C     = (const float*)d_in[5];
  const float* D_skip  = (const float*)d_in[6];
  const float* norm_w  = (const float*)d_in[7];
  float* y = (float*)d_out;

  char* ws = (char*)d_ws;
  const size_t MB = 1024 * 1024;
  _Float16* xnh = (_Float16*)(ws);                    //  8 MB xn f16
  _Float16* Wt  = (_Float16*)(ws + 8 * MB);           //  2 MB W_delta^T f16
  _Float16* BCe = (_Float16*)(ws + 10 * MB);          // 64 KB planar W_B/W_C f16 (32 x 1024)
  float*    bpc = (float*)(ws + 10 * MB + 512 * 1024);// 512 KB BC result [4096][32] planar
  half2_t*  sxh = (half2_t*)(ws + 11 * MB);           // 16 MB packed {sqrt(delta), xn}
  float2*   Ph  = (float2*)(ws + 27 * MB);            // 16 MB {prodA, h_end}
  float*    Hin = (float*)(ws + 43 * MB);             //  8 MB chunk-entry states
  (void)ws_size; (void)in_sizes; (void)n_in; (void)out_size;

  hipLaunchKernelGGL(k_prep_norm, dim3(4368), dim3(256), 0, stream,
                     x, norm_w, W_delta, W_B, W_C, xnh, Wt, BCe);
  hipLaunchKernelGGL(k_gemm64, dim3(512), dim3(256), 0, stream,
                     xnh, Wt, BCe, b_delta, sxh, bpc);
  hipLaunchKernelGGL(k_scan1, dim3(4, NCHUNK), dim3(256), 0, stream,
                     sxh, bpc, A_log, Ph);
  hipLaunchKernelGGL(k_comb, dim3(256), dim3(64), 0, stream, Ph, Hin);
  hipLaunchKernelGGL(k_scan2, dim3(4, NCHUNK), dim3(256), 0, stream,
                     sxh, bpc, A_log, Hin, D_skip, y);
}

// Round 3
// 158.504 us; speedup vs baseline: 1.0558x; 1.0025x over previous
//
#include <hip/hip_runtime.h>
#include <hip/hip_fp16.h>
#include <cmath>

typedef _Float16 half8 __attribute__((ext_vector_type(8)));
typedef _Float16 half4_t __attribute__((ext_vector_type(4)));
typedef _Float16 half2_t __attribute__((ext_vector_type(2)));
typedef float f32x4 __attribute__((ext_vector_type(4)));
typedef float f32x2 __attribute__((ext_vector_type(2)));

#define LDIM 4096
#define DDIM 1024
#define NSTATE 16
#define NCHUNK 128
#define CLEN 32

#define GLD16(g, l) __builtin_amdgcn_global_load_lds( \
    (const __attribute__((address_space(1))) void*)(g), \
    (__attribute__((address_space(3))) void*)(l), 16, 0, 0)

// ---------------- K1: prep (W transpose + BC pack planar) + RMSNorm ----------------
__global__ __launch_bounds__(256) void k_prep_norm(const float* __restrict__ x,
                                                   const float* __restrict__ nw,
                                                   const float* __restrict__ W,
                                                   const float* __restrict__ WB,
                                                   const float* __restrict__ WC,
                                                   _Float16* __restrict__ xnh,
                                                   _Float16* __restrict__ Wt,
                                                   _Float16* __restrict__ BCe) {
  const int b = blockIdx.x, t = threadIdx.x;
  if (b < 4096) {
    const int l = b;
    float4 v = ((const float4*)(x + (size_t)l * DDIM))[t];
    float ss = v.x * v.x + v.y * v.y + v.z * v.z + v.w * v.w;
#pragma unroll
    for (int off = 32; off; off >>= 1) ss += __shfl_xor(ss, off, 64);
    __shared__ float sred[4];
    if ((t & 63) == 0) sred[t >> 6] = ss;
    __syncthreads();
    float tot = sred[0] + sred[1] + sred[2] + sred[3];
    float r = rsqrtf(tot * (1.0f / (float)DDIM) + 1e-6f);
    float4 wv = ((const float4*)nw)[t];
    half4_t h;
    h[0] = (_Float16)(v.x * wv.x * r); h[1] = (_Float16)(v.y * wv.y * r);
    h[2] = (_Float16)(v.z * wv.z * r); h[3] = (_Float16)(v.w * wv.w * r);
    ((half4_t*)(xnh + (size_t)l * DDIM))[t] = h;
  } else if (b < 4352) {
    __shared__ float tile[64][65];
    const int bb = b - 4096;
    const int n0 = (bb & 15) * 64, k0 = (bb >> 4) * 64;
#pragma unroll
    for (int i = 0; i < 16; ++i) {
      int idx = t + i * 256;
      int kk = idx >> 6, nn = idx & 63;
      tile[kk][nn] = W[(size_t)(k0 + kk) * DDIM + n0 + nn];
    }
    __syncthreads();
#pragma unroll
    for (int i = 0; i < 16; ++i) {
      int idx = t + i * 256;
      int nn = idx >> 6, kk = idx & 63;
      Wt[(size_t)(n0 + nn) * DDIM + k0 + kk] = (_Float16)tile[kk][nn];
    }
  } else {
    // planar pack: rows 0..15 = W_B cols, rows 16..31 = W_C cols
    const int by2 = b - 4352;
#pragma unroll
    for (int rr = 0; rr < 2; ++rr) {
      int r = 2 * by2 + rr;
      const float* src = (r < 16) ? WB : WC;
      int n = r & 15;
#pragma unroll
      for (int j = 0; j < 4; ++j) {
        int k = t * 4 + j;
        BCe[(size_t)r * DDIM + k] = (_Float16)src[(size_t)k * NSTATE + n];
      }
    }
  }
}

// ---------------- K2: GEMM, BK=64, XOR-swizzled LDS, XCD-local bid remap ----------------
// Remap: bx = bid>>5, by = (bid&7) + ((bid>>3)&3)*8. Dispatch puts bid%8 on XCD bid%8,
// so all 16 bx-blocks sharing an A-panel (same by) land on ONE XCD: A panel (256KB)
// + full Wt (2MB) stay resident in that XCD's 4MB L2 -> staging becomes L2-hits.
__global__ __launch_bounds__(256, 2) void k_gemm64(const _Float16* __restrict__ Ah,
                                                   const _Float16* __restrict__ Bh,
                                                   const _Float16* __restrict__ B2h,
                                                   const float* __restrict__ b_delta,
                                                   half2_t* __restrict__ sxh,
                                                   float* __restrict__ bpc) {
  __shared__ __align__(16) _Float16 As[2][128 * 64];   // 32 KB
  __shared__ __align__(16) _Float16 Bs[2][64 * 64];    // 16 KB
  __shared__ __align__(16) _Float16 B2s[2][32 * 64];   //  8 KB
  const int t = threadIdx.x;
  const int w = t >> 6, lane = t & 63;
  const int quad = lane >> 4, l16 = lane & 15;
  const int wr = w >> 1, wc = w & 1;
  const int bid = blockIdx.x;
  const int bx = bid >> 5;                       // 0..15 (N)
  const int by = (bid & 7) + ((bid >> 3) & 3) * 8; // 0..31 (M), XCD-grouped
  const int tileM = by * 128, tileN = bx * 64;
  const int srow = lane >> 3;
  const int sslot = (lane & 7) ^ srow;   // pre-swizzled 16B slot in global source
  const _Float16* gA0 = Ah + (size_t)(tileM + w * 32 + srow) * DDIM + sslot * 8;
  const _Float16* gB0 = Bh + (size_t)(tileN + w * 16 + srow) * DDIM + sslot * 8;
  const _Float16* gC0 = B2h + (size_t)(w * 8 + srow) * DDIM + sslot * 8;

  f32x4 acc[4][2], acc2[4];
#pragma unroll
  for (int i = 0; i < 4; ++i) {
    acc2[i] = (f32x4){0.f, 0.f, 0.f, 0.f};
#pragma unroll
    for (int j = 0; j < 2; ++j) acc[i][j] = (f32x4){0.f, 0.f, 0.f, 0.f};
  }

  auto stage = [&](int kt, int p) {
    const int ko = kt * 64;
#pragma unroll
    for (int g = 0; g < 4; ++g)
      GLD16(gA0 + (size_t)g * 8 * DDIM + ko, &As[p][(w * 32 + g * 8) * 64]);
#pragma unroll
    for (int g = 0; g < 2; ++g)
      GLD16(gB0 + (size_t)g * 8 * DDIM + ko, &Bs[p][(w * 16 + g * 8) * 64]);
    if (bx == 0)
      GLD16(gC0 + ko, &B2s[p][(w * 8) * 64]);
  };

  stage(0, 0);
  for (int kt = 0; kt < 16; ++kt) {
    const int p = kt & 1;
    __syncthreads();               // drains vmcnt: buf p staged; guards p^1 overwrite
    if (kt < 15) stage(kt + 1, p ^ 1);
#pragma unroll
    for (int ks = 0; ks < 2; ++ks) {
      const int sw = ((ks * 4 + quad) ^ (l16 & 7)) * 8;  // swizzled 16B slot (halfs)
      half8 af[4], bf[2];
#pragma unroll
      for (int i = 0; i < 4; ++i)
        af[i] = *(const half8*)&As[p][(wr * 64 + i * 16 + l16) * 64 + sw];
#pragma unroll
      for (int j = 0; j < 2; ++j)
        bf[j] = *(const half8*)&Bs[p][(wc * 32 + j * 16 + l16) * 64 + sw];
#pragma unroll
      for (int i = 0; i < 4; ++i)
#pragma unroll
        for (int j = 0; j < 2; ++j)
          acc[i][j] = __builtin_amdgcn_mfma_f32_16x16x32_f16(af[i], bf[j], acc[i][j], 0, 0, 0);
      if (bx == 0) {
        half8 cf = *(const half8*)&B2s[p][(wc * 16 + l16) * 64 + sw];
#pragma unroll
        for (int i = 0; i < 4; ++i)
          acc2[i] = __builtin_amdgcn_mfma_f32_16x16x32_f16(af[i], cf, acc2[i], 0, 0, 0);
      }
    }
  }

  // epilogue: delta = soft_clamp(softplus(z+b)); write {sqrt(delta), xn} packed
  const float cC = 5.00005f, cH = 4.99995f, invH = 1.0f / 4.99995f;
  float bdl[2];
#pragma unroll
  for (int j = 0; j < 2; ++j) bdl[j] = b_delta[tileN + wc * 32 + j * 16 + l16];
#pragma unroll
  for (int i = 0; i < 4; ++i) {
#pragma unroll
    for (int r = 0; r < 4; ++r) {
      int row = tileM + wr * 64 + i * 16 + quad * 4 + r;
#pragma unroll
      for (int j = 0; j < 2; ++j) {
        int col = tileN + wc * 32 + j * 16 + l16;
        float z = acc[i][j][r] + bdl[j];
        float e = __expf(-fabsf(z));
        float sp = fmaxf(z, 0.f) + __logf(1.0f + e);
        float tt = (sp - cC) * invH;           // tt in [-1, ~1]: exp(2tt) safe
        float e2 = __expf(2.0f * tt);
        float th = 1.0f - 2.0f * __builtin_amdgcn_rcpf(e2 + 1.0f);
        float dt = fmaf(cH, th, cC);
        half2_t pk;
        pk[0] = (_Float16)sqrtf(dt);
        pk[1] = Ah[(size_t)row * DDIM + col];
        sxh[(size_t)row * DDIM + col] = pk;
      }
      if (bx == 0)
        bpc[(size_t)row * 32 + wc * 16 + l16] = acc2[i][r];
    }
  }
}

// ---------------- K3: per-chunk local scan -> {prodA, h_end} ----------------
// 4-way n-split: quad lanes share d, each handles n = q*4..q*4+3. Grid 2048 blocks
// -> 8 blocks/CU, target 8 waves/SIMD (launch_bounds(256,8)) for latency hiding.
// bc coefs staged in 4KB LDS (coalesced float4; reads are quad-broadcasts).
__global__ __launch_bounds__(256, 8) void k_scan1(const half2_t* __restrict__ sxh,
                                                  const float* __restrict__ bpc,
                                                  const float* __restrict__ A_log,
                                                  float2* __restrict__ Ph) {
  __shared__ __align__(16) float bcs[CLEN * 32];   // [i][B 0..15 | C 0..15]
  const int t = threadIdx.x;
  const int q = t & 3;                  // n-quarter
  const int d = blockIdx.x * 64 + (t >> 2);
  const int c = blockIdx.y;
  ((float4*)bcs)[t] = ((const float4*)(bpc + (size_t)c * CLEN * 32))[t];
  float4 al = *(const float4*)(A_log + (size_t)d * NSTATE + q * 4);
  f32x2 halfA[2], h[2], P[2];
  halfA[0] = (f32x2){-0.5f * __expf(al.x), -0.5f * __expf(al.y)};
  halfA[1] = (f32x2){-0.5f * __expf(al.z), -0.5f * __expf(al.w)};
  h[0] = h[1] = (f32x2){0.f, 0.f};
  P[0] = P[1] = (f32x2){1.f, 1.f};
  __syncthreads();
  const half2_t* sxr = sxh + (size_t)c * CLEN * DDIM + d;
  const f32x2 one2 = {1.f, 1.f}, two2 = {2.f, 2.f}, mone2 = {-1.f, -1.f};
#pragma unroll 4
  for (int i = 0; i < CLEN; ++i) {
    half2_t sx = sxr[(size_t)i * DDIM];
    float sdv = (float)sx[0], xv = (float)sx[1];
    float dsq = sdv * sdv, sdx = sdv * xv;
    f32x2 dsq2 = {dsq, dsq}, sdx2 = {sdx, sdx};
    f32x4 bB = *(const f32x4*)&bcs[i * 32 + q * 4];
#pragma unroll
    for (int j = 0; j < 2; ++j) {
      f32x2 bb = (f32x2){bB[2 * j], bB[2 * j + 1]};
      f32x2 hd = dsq2 * halfA[j];
      f32x2 om = one2 - hd;
      f32x2 di = {__builtin_amdgcn_rcpf(om[0]), __builtin_amdgcn_rcpf(om[1])};
      f32x2 ab = __builtin_elementwise_fma(di, two2, mone2);
      h[j] = __builtin_elementwise_fma(ab, h[j], sdx2 * bb * di);
      P[j] = P[j] * ab;
    }
  }
#pragma unroll
  for (int j = 0; j < 2; ++j) {
    Ph[((size_t)c * NSTATE + q * 4 + 2 * j + 0) * DDIM + d] = make_float2(P[j][0], h[j][0]);
    Ph[((size_t)c * NSTATE + q * 4 + 2 * j + 1) * DDIM + d] = make_float2(P[j][1], h[j][1]);
  }
}

// ---------------- K4: sequential combine across chunks ----------------
__global__ __launch_bounds__(64) void k_comb(const float2* __restrict__ Ph,
                                             float* __restrict__ Hinit) {
  const int g = blockIdx.x * 64 + threadIdx.x;
  float H = 0.f;
  for (int cb = 0; cb < NCHUNK; cb += 16) {
    float2 ph[16];
#pragma unroll
    for (int u = 0; u < 16; ++u)
      ph[u] = Ph[(size_t)(cb + u) * (DDIM * NSTATE) + g];
#pragma unroll
    for (int u = 0; u < 16; ++u) {
      Hinit[(size_t)(cb + u) * (DDIM * NSTATE) + g] = H;
      H = fmaf(ph[u].x, H, ph[u].y);
    }
  }
}

// ---------------- K5: re-run chunk scans with true h0, emit y ----------------
__global__ __launch_bounds__(256, 8) void k_scan2(const half2_t* __restrict__ sxh,
                                                  const float* __restrict__ bpc,
                                                  const float* __restrict__ A_log,
                                                  const float* __restrict__ Hinit,
                                                  const float* __restrict__ Dskip,
                                                  float* __restrict__ y) {
  __shared__ __align__(16) float bcs[CLEN * 32];
  const int t = threadIdx.x;
  const int q = t & 3;
  const int d = blockIdx.x * 64 + (t >> 2);
  const int c = blockIdx.y;
  ((float4*)bcs)[t] = ((const float4*)(bpc + (size_t)c * CLEN * 32))[t];
  float4 al = *(const float4*)(A_log + (size_t)d * NSTATE + q * 4);
  f32x2 halfA[2], h[2];
  halfA[0] = (f32x2){-0.5f * __expf(al.x), -0.5f * __expf(al.y)};
  halfA[1] = (f32x2){-0.5f * __expf(al.z), -0.5f * __expf(al.w)};
  const float* hb = Hinit + (size_t)c * (DDIM * NSTATE) + d;
  h[0] = (f32x2){hb[(size_t)(q * 4 + 0) * DDIM], hb[(size_t)(q * 4 + 1) * DDIM]};
  h[1] = (f32x2){hb[(size_t)(q * 4 + 2) * DDIM], hb[(size_t)(q * 4 + 3) * DDIM]};
  const float dsk = Dskip[d];
  __syncthreads();
  const half2_t* sxr = sxh + (size_t)c * CLEN * DDIM + d;
  float* yr = y + (size_t)c * CLEN * DDIM + d;
  const f32x2 one2 = {1.f, 1.f}, two2 = {2.f, 2.f}, mone2 = {-1.f, -1.f};
#pragma unroll 4
  for (int i = 0; i < CLEN; ++i) {
    half2_t sx = sxr[(size_t)i * DDIM];
    float sdv = (float)sx[0], xv = (float)sx[1];
    float dsq = sdv * sdv, sdx = sdv * xv;
    f32x2 dsq2 = {dsq, dsq}, sdx2 = {sdx, sdx};
    f32x4 bB = *(const f32x4*)&bcs[i * 32 + q * 4];
    f32x4 bC = *(const f32x4*)&bcs[i * 32 + 16 + q * 4];
    f32x2 acc = {0.f, 0.f};
#pragma unroll
    for (int j = 0; j < 2; ++j) {
      f32x2 bb = (f32x2){bB[2 * j], bB[2 * j + 1]};
      f32x2 cc = (f32x2){bC[2 * j], bC[2 * j + 1]};
      f32x2 hd = dsq2 * halfA[j];
      f32x2 om = one2 - hd;
      f32x2 di = {__builtin_amdgcn_rcpf(om[0]), __builtin_amdgcn_rcpf(om[1])};
      f32x2 ab = __builtin_elementwise_fma(di, two2, mone2);
      h[j] = __builtin_elementwise_fma(ab, h[j], sdx2 * bb * di);
      acc = __builtin_elementwise_fma(cc, h[j], acc);
    }
    float a = acc[0] + acc[1];
    a += __shfl_xor(a, 1, 64);
    a += __shfl_xor(a, 2, 64);
    if (q == 0) yr[(size_t)i * DDIM] = fmaf(dsk, xv, a);
  }
}

// ---------------- launch ----------------
extern "C" void kernel_launch(void* const* d_in, const int* in_sizes, int n_in,
                              void* d_out, int out_size, void* d_ws, size_t ws_size,
                              hipStream_t stream) {
  const float* x       = (const float*)d_in[0];
  const float* A_log   = (const float*)d_in[1];
  const float* W_delta = (const float*)d_in[2];
  const float* b_delta = (const float*)d_in[3];
  const float* W_B     = (const float*)d_in[4];
  const float* W_C     = (const float*)d_in[5];
  const float* D_skip  = (const float*)d_in[6];
  const float* norm_w  = (const float*)d_in[7];
  float* y = (float*)d_out;

  char* ws = (char*)d_ws;
  const size_t MB = 1024 * 1024;
  _Float16* xnh = (_Float16*)(ws);                    //  8 MB xn f16
  _Float16* Wt  = (_Float16*)(ws + 8 * MB);           //  2 MB W_delta^T f16
  _Float16* BCe = (_Float16*)(ws + 10 * MB);          // 64 KB planar W_B/W_C f16 (32 x 1024)
  float*    bpc = (float*)(ws + 10 * MB + 512 * 1024);// 512 KB BC result [4096][32] planar
  half2_t*  sxh = (half2_t*)(ws + 11 * MB);           // 16 MB packed {sqrt(delta), xn}
  float2*   Ph  = (float2*)(ws + 27 * MB);            // 16 MB {prodA, h_end}
  float*    Hin = (float*)(ws + 43 * MB);             //  8 MB chunk-entry states
  (void)ws_size; (void)in_sizes; (void)n_in; (void)out_size;

  hipLaunchKernelGGL(k_prep_norm, dim3(4368), dim3(256), 0, stream,
                     x, norm_w, W_delta, W_B, W_C, xnh, Wt, BCe);
  hipLaunchKernelGGL(k_gemm64, dim3(512), dim3(256), 0, stream,
                     xnh, Wt, BCe, b_delta, sxh, bpc);
  hipLaunchKernelGGL(k_scan1, dim3(16, NCHUNK), dim3(256), 0, stream,
                     sxh, bpc, A_log, Ph);
  hipLaunchKernelGGL(k_comb, dim3(256), dim3(64), 0, stream, Ph, Hin);
  hipLaunchKernelGGL(k_scan2, dim3(16, NCHUNK), dim3(256), 0, stream,
                     sxh, bpc, A_log, Hin, D_skip, y);
}